// Round 8
// baseline (1875.341 us; speedup 1.0000x reference)
//
#include <hip/hip_runtime.h>
#include <math.h>

#define DD 128      // hidden dim
#define ANND 64     // annotation dim
#define NSTEPS 5
#define NTYPES 4
#define NCLS 10

typedef __attribute__((ext_vector_type(8))) short short8v;  // 8 bf16
typedef __attribute__((ext_vector_type(4))) float f32x4;

// split fp32 into hi+lo bf16 (RNE both)
__device__ __forceinline__ void split2(float x, unsigned short& hi, unsigned short& lo) {
  unsigned u = __float_as_uint(x);
  unsigned hb = (u + 0x7FFFu + ((u >> 16) & 1u)) >> 16;
  hi = (unsigned short)hb;
  float r = x - __uint_as_float(hb << 16);
  unsigned v = __float_as_uint(r);
  lo = (unsigned short)((v + 0x7FFFu + ((v >> 16) & 1u)) >> 16);
}

__device__ __forceinline__ float bf2f(unsigned short u) {
  return __uint_as_float(((unsigned)u) << 16);
}
__device__ __forceinline__ float rec2(const unsigned short* hi, const unsigned short* lo, size_t i) {
  return bf2f(hi[i]) + bf2f(lo[i]);
}
__device__ __forceinline__ float lo16f(unsigned u) { return __uint_as_float(u << 16); }
__device__ __forceinline__ float hi16f(unsigned u) { return __uint_as_float(u & 0xffff0000u); }

// h = [ann | 0] as split planes; zero-fill padded rows [n, npad)
__global__ void k_init(const float* __restrict__ ann,
    unsigned short* __restrict__ hhi, unsigned short* __restrict__ hlo, int n, int npad) {
  int idx = blockIdx.x * blockDim.x + threadIdx.x;
  if (idx >= npad * DD) return;
  int node = idx >> 7, d = idx & 127;
  float v = (node < n && d < ANND) ? ann[node * ANND + d] : 0.0f;
  unsigned short hi, lo; split2(v, hi, lo);
  hhi[idx] = hi; hlo[idx] = lo;
}

// ---------- CSR build (by dst), once per launch ----------
__global__ void k_deg4(const int* __restrict__ dst, const int* __restrict__ et,
    int* __restrict__ deg4, int e) {
  int i = blockIdx.x * blockDim.x + threadIdx.x;
  if (i < e) atomicAdd(&deg4[dst[i] * 4 + et[i]], 1);
}

// exclusive scan over per-node total degree (sum of deg4) -> base[0..n]
__global__ __launch_bounds__(1024) void k_scan(const int* __restrict__ deg4,
    int* __restrict__ base, int n) {
  __shared__ int part[1024];
  int t = threadIdx.x;
  int chunk = (n + 1023) >> 10;
  int s = t * chunk, e = min(n, s + chunk);
  int sum = 0;
  for (int i = s; i < e; ++i) {
    const int4 d4 = *(const int4*)(deg4 + (size_t)i * 4);
    sum += d4.x + d4.y + d4.z + d4.w;
  }
  part[t] = sum;
  __syncthreads();
  int own = sum;
  for (int off = 1; off < 1024; off <<= 1) {
    int v = (t >= off) ? part[t - off] : 0;
    __syncthreads();
    part[t] += v;
    __syncthreads();
  }
  int run = part[t] - own;
  for (int i = s; i < e; ++i) {
    base[i] = run;
    const int4 d4 = *(const int4*)(deg4 + (size_t)i * 4);
    run += d4.x + d4.y + d4.z + d4.w;
  }
  if (s < n && e == n) base[n] = run;
}

// pack (et<<18)|src into one CSR payload array
__global__ void k_place(const int* __restrict__ src, const int* __restrict__ dst,
    const int* __restrict__ et, const int* __restrict__ base, int* __restrict__ cursor,
    int* __restrict__ cpack, int e) {
  int i = blockIdx.x * blockDim.x + threadIdx.x;
  if (i >= e) return;
  int d = dst[i];
  int pos = base[d] + atomicAdd(&cursor[d], 1);
  cpack[pos] = src[i] | (et[i] << 18);
}

// ---------- per-type neighbor sums: one WAVE per node, shfl-broadcast indices ----------
__global__ void k_aggh(const unsigned* __restrict__ hhiU, const unsigned* __restrict__ hloU,
    const int* __restrict__ base, const int* __restrict__ cpack,
    unsigned* __restrict__ A3hiU, unsigned* __restrict__ A3loU, int nbase, int cc) {
  int w = threadIdx.x >> 6;          // wave in block: 0..3
  int lane = threadIdx.x & 63;       // c-pair index (covers c=2*lane, 2*lane+1)
  int local = blockIdx.x * 4 + w;
  if (local >= cc) return;
  int node = nbase + local;
  int s = base[node], e = base[node + 1];
  float a0x = 0.f, a0y = 0.f, a1x = 0.f, a1y = 0.f;
  float a2x = 0.f, a2y = 0.f, a3x = 0.f, a3y = 0.f;
  for (int t0 = s; t0 < e; t0 += 64) {
    int cnt = min(64, e - t0);
    int mypk = (t0 + lane < e) ? cpack[t0 + lane] : 0;
    int i = 0;
    for (; i + 4 <= cnt; i += 4) {
      int pk0 = __shfl(mypk, i), pk1 = __shfl(mypk, i + 1);
      int pk2 = __shfl(mypk, i + 2), pk3 = __shfl(mypk, i + 3);
      unsigned uh0 = hhiU[(size_t)(pk0 & 0x3ffff) * 64 + lane];
      unsigned ul0 = hloU[(size_t)(pk0 & 0x3ffff) * 64 + lane];
      unsigned uh1 = hhiU[(size_t)(pk1 & 0x3ffff) * 64 + lane];
      unsigned ul1 = hloU[(size_t)(pk1 & 0x3ffff) * 64 + lane];
      unsigned uh2 = hhiU[(size_t)(pk2 & 0x3ffff) * 64 + lane];
      unsigned ul2 = hloU[(size_t)(pk2 & 0x3ffff) * 64 + lane];
      unsigned uh3 = hhiU[(size_t)(pk3 & 0x3ffff) * 64 + lane];
      unsigned ul3 = hloU[(size_t)(pk3 & 0x3ffff) * 64 + lane];
      float v0x = lo16f(uh0) + lo16f(ul0), v0y = hi16f(uh0) + hi16f(ul0);
      float v1x = lo16f(uh1) + lo16f(ul1), v1y = hi16f(uh1) + hi16f(ul1);
      float v2x = lo16f(uh2) + lo16f(ul2), v2y = hi16f(uh2) + hi16f(ul2);
      float v3x = lo16f(uh3) + lo16f(ul3), v3y = hi16f(uh3) + hi16f(ul3);
      int t;
      t = pk0 >> 18;
      if (t == 0) { a0x += v0x; a0y += v0y; } else if (t == 1) { a1x += v0x; a1y += v0y; }
      else if (t == 2) { a2x += v0x; a2y += v0y; } else { a3x += v0x; a3y += v0y; }
      t = pk1 >> 18;
      if (t == 0) { a0x += v1x; a0y += v1y; } else if (t == 1) { a1x += v1x; a1y += v1y; }
      else if (t == 2) { a2x += v1x; a2y += v1y; } else { a3x += v1x; a3y += v1y; }
      t = pk2 >> 18;
      if (t == 0) { a0x += v2x; a0y += v2y; } else if (t == 1) { a1x += v2x; a1y += v2y; }
      else if (t == 2) { a2x += v2x; a2y += v2y; } else { a3x += v2x; a3y += v2y; }
      t = pk3 >> 18;
      if (t == 0) { a0x += v3x; a0y += v3y; } else if (t == 1) { a1x += v3x; a1y += v3y; }
      else if (t == 2) { a2x += v3x; a2y += v3y; } else { a3x += v3x; a3y += v3y; }
    }
    for (; i < cnt; ++i) {
      int pk = __shfl(mypk, i);
      unsigned uh = hhiU[(size_t)(pk & 0x3ffff) * 64 + lane];
      unsigned ul = hloU[(size_t)(pk & 0x3ffff) * 64 + lane];
      float vx = lo16f(uh) + lo16f(ul), vy = hi16f(uh) + hi16f(ul);
      int t = pk >> 18;
      if (t == 0) { a0x += vx; a0y += vy; } else if (t == 1) { a1x += vx; a1y += vy; }
      else if (t == 2) { a2x += vx; a2y += vy; } else { a3x += vx; a3y += vy; }
    }
  }
  size_t bu = (size_t)local * 256 + lane;
  unsigned short h0, l0, h1, l1;
  split2(a0x, h0, l0); split2(a0y, h1, l1);
  A3hiU[bu] = (unsigned)h0 | ((unsigned)h1 << 16);
  A3loU[bu] = (unsigned)l0 | ((unsigned)l1 << 16);
  split2(a1x, h0, l0); split2(a1y, h1, l1);
  A3hiU[bu + 64] = (unsigned)h0 | ((unsigned)h1 << 16);
  A3loU[bu + 64] = (unsigned)l0 | ((unsigned)l1 << 16);
  split2(a2x, h0, l0); split2(a2y, h1, l1);
  A3hiU[bu + 128] = (unsigned)h0 | ((unsigned)h1 << 16);
  A3loU[bu + 128] = (unsigned)l0 | ((unsigned)l1 << 16);
  split2(a3x, h0, l0); split2(a3y, h1, l1);
  A3hiU[bu + 192] = (unsigned)h0 | ((unsigned)h1 << 16);
  A3loU[bu + 192] = (unsigned)l0 | ((unsigned)l1 << 16);
}

// ---------- MFMA GEMM (a-computation): C = A3 @ WlT^T + deg-bias, split store ----------
// 512 threads: 8 waves = 4 row-groups x 2 col-groups; block = 128 rows x 64 cols
__global__ __launch_bounds__(512) void k_gemm_a(
    const unsigned short* __restrict__ Ahi, const unsigned short* __restrict__ Alo,
    const unsigned short* __restrict__ Whi, const unsigned short* __restrict__ Wlo,
    const float* __restrict__ bias, const int* __restrict__ deg4,
    unsigned short* __restrict__ Chi, unsigned short* __restrict__ Clo, int n) {
  int wid = threadIdx.x >> 6, lane = threadIdx.x & 63;
  int rowbase = blockIdx.x * 128 + (wid >> 1) * 32;
  int colbase = blockIdx.y * 64 + (wid & 1) * 32;
  int lr = lane & 15, lk = lane >> 4;
  f32x4 acc[2][2];
  #pragma unroll
  for (int nn = 0; nn < 2; ++nn)
    #pragma unroll
    for (int mm = 0; mm < 2; ++mm) acc[mm][nn] = (f32x4){0.f, 0.f, 0.f, 0.f};
  for (int k0 = 0; k0 < 512; k0 += 32) {
    int koff = k0 + lk * 8;
    short8v ah[2], al[2], bh[2], bl[2];
    #pragma unroll
    for (int mm = 0; mm < 2; ++mm) {
      size_t off = (size_t)(rowbase + mm * 16 + lr) * 512 + koff;
      ah[mm] = *(const short8v*)(Ahi + off);
      al[mm] = *(const short8v*)(Alo + off);
    }
    #pragma unroll
    for (int nn = 0; nn < 2; ++nn) {
      size_t off = (size_t)(colbase + nn * 16 + lr) * 512 + koff;
      bh[nn] = *(const short8v*)(Whi + off);
      bl[nn] = *(const short8v*)(Wlo + off);
    }
    #pragma unroll
    for (int mm = 0; mm < 2; ++mm)
      #pragma unroll
      for (int nn = 0; nn < 2; ++nn) {
        acc[mm][nn] = __builtin_amdgcn_mfma_f32_16x16x32_bf16(ah[mm], bh[nn], acc[mm][nn], 0, 0, 0);
        acc[mm][nn] = __builtin_amdgcn_mfma_f32_16x16x32_bf16(ah[mm], bl[nn], acc[mm][nn], 0, 0, 0);
        acc[mm][nn] = __builtin_amdgcn_mfma_f32_16x16x32_bf16(al[mm], bh[nn], acc[mm][nn], 0, 0, 0);
      }
  }
  #pragma unroll
  for (int mm = 0; mm < 2; ++mm) {
    #pragma unroll
    for (int j = 0; j < 4; ++j) {
      int row = rowbase + mm * 16 + lk * 4 + j;
      if (row < n) {
        int4 dg = *(const int4*)(deg4 + (size_t)row * 4);
        #pragma unroll
        for (int nn = 0; nn < 2; ++nn) {
          int col = colbase + nn * 16 + lr;
          float v = acc[mm][nn][j] + dg.x * bias[col] + dg.y * bias[128 + col]
                  + dg.z * bias[256 + col] + dg.w * bias[384 + col];
          unsigned short hi, lo; split2(v, hi, lo);
          Chi[(size_t)row * DD + col] = hi;
          Clo[(size_t)row * DD + col] = lo;
        }
      }
    }
  }
}

// ---------- fused GRU: gi+gh GEMMs + gate math, writes h' split planes ----------
// 512 threads: 8 waves = 4 row-groups x 2 col-groups; block = 128 rows x 64 cols
__global__ __launch_bounds__(512) void k_grufuse(
    const unsigned short* __restrict__ Ahi, const unsigned short* __restrict__ Alo,
    const unsigned short* __restrict__ Hhi, const unsigned short* __restrict__ Hlo,
    const unsigned short* __restrict__ WihH, const unsigned short* __restrict__ WihL,
    const unsigned short* __restrict__ WhhH, const unsigned short* __restrict__ WhhL,
    const float* __restrict__ bih, const float* __restrict__ bhh,
    unsigned short* __restrict__ Ohi, unsigned short* __restrict__ Olo,
    int nbase, int cc) {
  int wid = threadIdx.x >> 6, lane = threadIdx.x & 63;
  int rb = blockIdx.x * 128 + (wid >> 1) * 32;  // chunk-local row base
  int cb = blockIdx.y * 64 + (wid & 1) * 32;    // d col base
  int lr = lane & 15, lk = lane >> 4;
  f32x4 sr[2][2], sz[2][2], gn[2][2], hn[2][2];
  #pragma unroll
  for (int nn = 0; nn < 2; ++nn) {
    int col = cb + nn * 16 + lr;
    float br = bih[col] + bhh[col];
    float bz = bih[DD + col] + bhh[DD + col];
    float bi = bih[2 * DD + col];
    float bh = bhh[2 * DD + col];
    #pragma unroll
    for (int mm = 0; mm < 2; ++mm) {
      sr[mm][nn] = (f32x4){br, br, br, br};
      sz[mm][nn] = (f32x4){bz, bz, bz, bz};
      gn[mm][nn] = (f32x4){bi, bi, bi, bi};
      hn[mm][nn] = (f32x4){bh, bh, bh, bh};
    }
  }
  for (int k0 = 0; k0 < DD; k0 += 32) {
    int koff = k0 + lk * 8;
    short8v ah[2], al[2], hh_[2], hl_[2];
    #pragma unroll
    for (int mm = 0; mm < 2; ++mm) {
      size_t ao = (size_t)(rb + mm * 16 + lr) * DD + koff;
      ah[mm] = *(const short8v*)(Ahi + ao);
      al[mm] = *(const short8v*)(Alo + ao);
      size_t ho = (size_t)(nbase + rb + mm * 16 + lr) * DD + koff;
      hh_[mm] = *(const short8v*)(Hhi + ho);
      hl_[mm] = *(const short8v*)(Hlo + ho);
    }
    #pragma unroll
    for (int nn = 0; nn < 2; ++nn) {
      int c16 = cb + nn * 16 + lr;
      {  // r gate
        short8v wiH = *(const short8v*)(WihH + (size_t)c16 * DD + koff);
        short8v wiL = *(const short8v*)(WihL + (size_t)c16 * DD + koff);
        short8v whH = *(const short8v*)(WhhH + (size_t)c16 * DD + koff);
        short8v whL = *(const short8v*)(WhhL + (size_t)c16 * DD + koff);
        #pragma unroll
        for (int mm = 0; mm < 2; ++mm) {
          sr[mm][nn] = __builtin_amdgcn_mfma_f32_16x16x32_bf16(ah[mm], wiH, sr[mm][nn], 0, 0, 0);
          sr[mm][nn] = __builtin_amdgcn_mfma_f32_16x16x32_bf16(ah[mm], wiL, sr[mm][nn], 0, 0, 0);
          sr[mm][nn] = __builtin_amdgcn_mfma_f32_16x16x32_bf16(al[mm], wiH, sr[mm][nn], 0, 0, 0);
          sr[mm][nn] = __builtin_amdgcn_mfma_f32_16x16x32_bf16(hh_[mm], whH, sr[mm][nn], 0, 0, 0);
          sr[mm][nn] = __builtin_amdgcn_mfma_f32_16x16x32_bf16(hh_[mm], whL, sr[mm][nn], 0, 0, 0);
          sr[mm][nn] = __builtin_amdgcn_mfma_f32_16x16x32_bf16(hl_[mm], whH, sr[mm][nn], 0, 0, 0);
        }
      }
      {  // z gate
        int rz = DD + c16;
        short8v wiH = *(const short8v*)(WihH + (size_t)rz * DD + koff);
        short8v wiL = *(const short8v*)(WihL + (size_t)rz * DD + koff);
        short8v whH = *(const short8v*)(WhhH + (size_t)rz * DD + koff);
        short8v whL = *(const short8v*)(WhhL + (size_t)rz * DD + koff);
        #pragma unroll
        for (int mm = 0; mm < 2; ++mm) {
          sz[mm][nn] = __builtin_amdgcn_mfma_f32_16x16x32_bf16(ah[mm], wiH, sz[mm][nn], 0, 0, 0);
          sz[mm][nn] = __builtin_amdgcn_mfma_f32_16x16x32_bf16(ah[mm], wiL, sz[mm][nn], 0, 0, 0);
          sz[mm][nn] = __builtin_amdgcn_mfma_f32_16x16x32_bf16(al[mm], wiH, sz[mm][nn], 0, 0, 0);
          sz[mm][nn] = __builtin_amdgcn_mfma_f32_16x16x32_bf16(hh_[mm], whH, sz[mm][nn], 0, 0, 0);
          sz[mm][nn] = __builtin_amdgcn_mfma_f32_16x16x32_bf16(hh_[mm], whL, sz[mm][nn], 0, 0, 0);
          sz[mm][nn] = __builtin_amdgcn_mfma_f32_16x16x32_bf16(hl_[mm], whH, sz[mm][nn], 0, 0, 0);
        }
      }
      {  // n gate
        int rn = 2 * DD + c16;
        short8v wiH = *(const short8v*)(WihH + (size_t)rn * DD + koff);
        short8v wiL = *(const short8v*)(WihL + (size_t)rn * DD + koff);
        short8v whH = *(const short8v*)(WhhH + (size_t)rn * DD + koff);
        short8v whL = *(const short8v*)(WhhL + (size_t)rn * DD + koff);
        #pragma unroll
        for (int mm = 0; mm < 2; ++mm) {
          gn[mm][nn] = __builtin_amdgcn_mfma_f32_16x16x32_bf16(ah[mm], wiH, gn[mm][nn], 0, 0, 0);
          gn[mm][nn] = __builtin_amdgcn_mfma_f32_16x16x32_bf16(ah[mm], wiL, gn[mm][nn], 0, 0, 0);
          gn[mm][nn] = __builtin_amdgcn_mfma_f32_16x16x32_bf16(al[mm], wiH, gn[mm][nn], 0, 0, 0);
          hn[mm][nn] = __builtin_amdgcn_mfma_f32_16x16x32_bf16(hh_[mm], whH, hn[mm][nn], 0, 0, 0);
          hn[mm][nn] = __builtin_amdgcn_mfma_f32_16x16x32_bf16(hh_[mm], whL, hn[mm][nn], 0, 0, 0);
          hn[mm][nn] = __builtin_amdgcn_mfma_f32_16x16x32_bf16(hl_[mm], whH, hn[mm][nn], 0, 0, 0);
        }
      }
    }
  }
  #pragma unroll
  for (int mm = 0; mm < 2; ++mm) {
    #pragma unroll
    for (int j = 0; j < 4; ++j) {
      int row = rb + mm * 16 + lk * 4 + j;
      if (row < cc) {
        #pragma unroll
        for (int nn = 0; nn < 2; ++nn) {
          int col = cb + nn * 16 + lr;
          float r = 1.f / (1.f + expf(-sr[mm][nn][j]));
          float z = 1.f / (1.f + expf(-sz[mm][nn][j]));
          float nt = tanhf(gn[mm][nn][j] + r * hn[mm][nn][j]);
          size_t gidx = (size_t)(nbase + row) * DD + col;
          float hv = (1.f - z) * nt + z * rec2(Hhi, Hlo, gidx);
          unsigned short uh, ul; split2(hv, uh, ul);
          Ohi[gidx] = uh; Olo[gidx] = ul;
        }
      }
    }
  }
}

// ---------- weight prep ----------
__global__ void k_repack_wlin(const float* __restrict__ W,
    unsigned short* __restrict__ hi_, unsigned short* __restrict__ lo_) {
  int idx = blockIdx.x * blockDim.x + threadIdx.x;
  if (idx >= 128 * 512) return;
  int o = idx >> 9, kd = idx & 511;
  int k = kd >> 7, d = kd & 127;
  float v = W[k * 16384 + o * 128 + d];
  unsigned short h, l; split2(v, h, l);
  hi_[idx] = h; lo_[idx] = l;
}

__global__ void k_splitw(const float* __restrict__ x,
    unsigned short* __restrict__ hi_, unsigned short* __restrict__ lo_, int n) {
  int i = blockIdx.x * blockDim.x + threadIdx.x;
  if (i >= n) return;
  unsigned short h, l; split2(x[i], h, l);
  hi_[i] = h; lo_[i] = l;
}

// ---------- readout ----------
__global__ void k_gate(const unsigned short* __restrict__ hhi,
    const unsigned short* __restrict__ hlo, const float* __restrict__ ann,
    const float* __restrict__ gw, const float* __restrict__ gb,
    float* __restrict__ gate, int n) {
  int gt = blockIdx.x * blockDim.x + threadIdx.x;
  int wv = gt >> 6;
  int lane = threadIdx.x & 63;
  if (wv >= n) return;
  float p = rec2(hhi, hlo, (size_t)wv * DD + lane) * gw[lane]
          + rec2(hhi, hlo, (size_t)wv * DD + 64 + lane) * gw[64 + lane]
          + ann[(size_t)wv * ANND + lane] * gw[128 + lane];
  for (int off = 32; off; off >>= 1) p += __shfl_down(p, off);
  if (lane == 0) gate[wv] = p + gb[0];
}

// sorted node2graph -> segment bounds via boundary detection (no atomics)
__global__ void k_bounds(const int* __restrict__ n2g, int* __restrict__ startg,
    int* __restrict__ endg, int n) {
  int i = blockIdx.x * blockDim.x + threadIdx.x;
  if (i >= n) return;
  int g = n2g[i];
  if (i == 0 || n2g[i - 1] != g) startg[g] = i;
  if (i == n - 1 || n2g[i + 1] != g) endg[g] = i + 1;
}

// per-graph softmax max + 1/denominator
__global__ __launch_bounds__(256) void k_mden(const float* __restrict__ gate,
    const int* __restrict__ startg, const int* __restrict__ endg,
    float* __restrict__ mg, float* __restrict__ invg) {
  __shared__ float red[256];
  int g = blockIdx.x;
  int s = startg[g], e = endg[g];
  int tid = threadIdx.x;
  float m = -1e30f;
  for (int i = s + tid; i < e; i += 256) m = fmaxf(m, gate[i]);
  red[tid] = m; __syncthreads();
  for (int off = 128; off; off >>= 1) {
    if (tid < off) red[tid] = fmaxf(red[tid], red[tid + off]);
    __syncthreads();
  }
  m = red[0];
  __syncthreads();
  float sum = 0.f;
  for (int i = s + tid; i < e; i += 256) sum += expf(gate[i] - m);
  red[tid] = sum; __syncthreads();
  for (int off = 128; off; off >>= 1) {
    if (tid < off) red[tid] += red[tid + off];
    __syncthreads();
  }
  if (tid == 0) { mg[g] = m; invg[g] = (s < e) ? 1.f / red[0] : 0.f; }
}

// weighted readout; grid (B, 2): y=0 h-dims (packed uint pairs), y=1 ann-dims
__global__ __launch_bounds__(256) void k_pool2(const float* __restrict__ gate,
    const unsigned* __restrict__ hhiU, const unsigned* __restrict__ hloU,
    const float* __restrict__ ann, const int* __restrict__ startg,
    const int* __restrict__ endg, const float* __restrict__ mg,
    const float* __restrict__ invg, float* __restrict__ readout) {
  __shared__ float redx[256], redy[256];
  int g = blockIdx.x;
  int s = startg[g], e = endg[g];
  int nl = threadIdx.x >> 6, lane = threadIdx.x & 63;
  float m = mg[g], inv = invg[g];
  if (blockIdx.y == 0) {
    float ax = 0.f, ay = 0.f;
    for (int i = s + nl; i < e; i += 4) {
      float al = expf(gate[i] - m) * inv;
      unsigned uh = hhiU[(size_t)i * 64 + lane];
      unsigned ul = hloU[(size_t)i * 64 + lane];
      ax += al * (lo16f(uh) + lo16f(ul));
      ay += al * (hi16f(uh) + hi16f(ul));
    }
    redx[threadIdx.x] = ax; redy[threadIdx.x] = ay;
    __syncthreads();
    if (nl == 0) {
      float sx = redx[lane] + redx[64 + lane] + redx[128 + lane] + redx[192 + lane];
      float sy = redy[lane] + redy[64 + lane] + redy[128 + lane] + redy[192 + lane];
      readout[g * (DD + ANND) + 2 * lane] = sx;
      readout[g * (DD + ANND) + 2 * lane + 1] = sy;
    }
  } else {
    float acc = 0.f;
    for (int i = s + nl; i < e; i += 4) {
      float al = expf(gate[i] - m) * inv;
      acc += al * ann[(size_t)i * ANND + lane];
    }
    redx[threadIdx.x] = acc;
    __syncthreads();
    if (nl == 0)
      readout[g * (DD + ANND) + DD + lane] =
          redx[lane] + redx[64 + lane] + redx[128 + lane] + redx[192 + lane];
  }
}

__global__ void k_logits(const float* __restrict__ readout, const float* __restrict__ ow,
    const float* __restrict__ ob, const int* __restrict__ labels,
    float* __restrict__ out, int B) {
  __shared__ float lsum[64];
  int g = threadIdx.x;
  float loss_c = 0.f;
  if (g < B) {
    float lg[NCLS];
    float mx = -1e30f;
    int best = 0;
    for (int c = 0; c < NCLS; ++c) {
      float acc = ob[c];
      const float* r = readout + g * (DD + ANND);
      const float* w = ow + c * (DD + ANND);
      for (int d = 0; d < DD + ANND; ++d) acc += r[d] * w[d];
      lg[c] = acc;
      if (acc > mx) { mx = acc; best = c; }
    }
    float se = 0.f;
    for (int c = 0; c < NCLS; ++c) se += expf(lg[c] - mx);
    float lse = mx + logf(se);
    loss_c = -(lg[labels[g]] - lse);
    out[1 + g] = (float)best;
  }
  lsum[threadIdx.x] = loss_c;
  __syncthreads();
  for (int off = 32; off; off >>= 1) {
    if (threadIdx.x < off) lsum[threadIdx.x] += lsum[threadIdx.x + off];
    __syncthreads();
  }
  if (threadIdx.x == 0) out[0] = lsum[0] / (float)B;
}

extern "C" void kernel_launch(void* const* d_in, const int* in_sizes, int n_in,
                              void* d_out, int out_size, void* d_ws, size_t ws_size,
                              hipStream_t stream) {
  const float* annotation = (const float*)d_in[0];
  const int*   src        = (const int*)d_in[1];
  const int*   dst        = (const int*)d_in[2];
  const int*   et         = (const int*)d_in[3];
  const int*   n2g        = (const int*)d_in[4];
  const int*   labels     = (const int*)d_in[5];
  const float* W_lin      = (const float*)d_in[6];
  const float* b_lin      = (const float*)d_in[7];
  const float* W_ih       = (const float*)d_in[8];
  const float* W_hh       = (const float*)d_in[9];
  const float* b_ih       = (const float*)d_in[10];
  const float* b_hh       = (const float*)d_in[11];
  const float* gate_w     = (const float*)d_in[12];
  const float* gate_b     = (const float*)d_in[13];
  const float* out_w      = (const float*)d_in[14];
  const float* out_b      = (const float*)d_in[15];

  int N = in_sizes[0] / ANND;
  int E = in_sizes[1];
  int B = in_sizes[5];
  int Np = (N + 127) & ~127;   // pad to 128-row tiles

  // ---- workspace budget: fixed allocations, then largest chunk that fits ----
  auto rup = [](size_t b) { return (b + 255) & ~(size_t)255; };
  size_t fixed = 0;
  fixed += 4 * rup((size_t)Np * DD * 2);           // h ping-pong planes
  fixed += rup((size_t)N * 4);                     // gate
  fixed += rup((size_t)B * (DD + ANND) * 4);       // readout
  fixed += 2 * rup((size_t)B * 4);                 // startg, endg
  fixed += 2 * rup((size_t)B * 4);                 // mg, invg
  fixed += rup((size_t)(N + 1) * 4);               // base
  fixed += rup((size_t)N * 4);                     // cursor
  fixed += rup((size_t)N * 16);                    // deg4
  fixed += rup((size_t)E * 4);                     // cpack
  fixed += 2 * rup(128 * 512 * 2) + 4 * rup(384 * 128 * 2);  // weights
  size_t slack = 1 << 20;
  size_t avail = (ws_size > fixed + slack) ? ws_size - fixed - slack : 0;
  long long ch = (long long)(avail / 2560);        // A3 + a planes per node
  int CH = (int)((ch / 128) * 128);
  if (CH < 128) CH = 128;
  if (CH > Np) CH = Np;

  char* wsP = (char*)d_ws;
  auto alloc = [&](size_t bytes) -> void* {
    void* p = (void*)wsP;
    wsP += (bytes + 255) & ~(size_t)255;
    return p;
  };
  unsigned short* hP_hi[2], *hP_lo[2];
  hP_hi[0] = (unsigned short*)alloc((size_t)Np * DD * 2);
  hP_lo[0] = (unsigned short*)alloc((size_t)Np * DD * 2);
  hP_hi[1] = (unsigned short*)alloc((size_t)Np * DD * 2);
  hP_lo[1] = (unsigned short*)alloc((size_t)Np * DD * 2);
  float* gate = (float*)alloc((size_t)N * 4);
  float* readout = (float*)alloc((size_t)B * (DD + ANND) * 4);
  int* startg = (int*)alloc((size_t)B * 4);
  int* endg   = (int*)alloc((size_t)B * 4);
  float* mg   = (float*)alloc((size_t)B * 4);
  float* invg = (float*)alloc((size_t)B * 4);
  int* base   = (int*)alloc((size_t)(N + 1) * 4);
  int* cursor = (int*)alloc((size_t)N * 4);
  int* deg4   = (int*)alloc((size_t)N * 16);
  int* cpack  = (int*)alloc((size_t)E * 4);
  unsigned short* WlT_hi = (unsigned short*)alloc(128 * 512 * 2);
  unsigned short* WlT_lo = (unsigned short*)alloc(128 * 512 * 2);
  unsigned short* Wih_hi = (unsigned short*)alloc(384 * 128 * 2);
  unsigned short* Wih_lo = (unsigned short*)alloc(384 * 128 * 2);
  unsigned short* Whh_hi = (unsigned short*)alloc(384 * 128 * 2);
  unsigned short* Whh_lo = (unsigned short*)alloc(384 * 128 * 2);
  unsigned short* A3hi = (unsigned short*)alloc((size_t)CH * 512 * 2);
  unsigned short* A3lo = (unsigned short*)alloc((size_t)CH * 512 * 2);
  unsigned short* a_hi = (unsigned short*)alloc((size_t)CH * DD * 2);
  unsigned short* a_lo = (unsigned short*)alloc((size_t)CH * DD * 2);

  // init + CSR + weight prep (once per launch)
  k_init<<<(Np * DD + 255) / 256, 256, 0, stream>>>(annotation, hP_hi[0], hP_lo[0], N, Np);
  hipMemsetAsync(cursor, 0, (size_t)N * 4, stream);
  hipMemsetAsync(deg4, 0, (size_t)N * 16, stream);
  hipMemsetAsync(startg, 0x7f, (size_t)B * 4, stream);
  hipMemsetAsync(endg, 0, (size_t)B * 4, stream);
  k_deg4<<<(E + 255) / 256, 256, 0, stream>>>(dst, et, deg4, E);
  k_scan<<<1, 1024, 0, stream>>>(deg4, base, N);
  k_place<<<(E + 255) / 256, 256, 0, stream>>>(src, dst, et, base, cursor, cpack, E);
  k_bounds<<<(N + 255) / 256, 256, 0, stream>>>(n2g, startg, endg, N);
  k_repack_wlin<<<(128 * 512 + 255) / 256, 256, 0, stream>>>(W_lin, WlT_hi, WlT_lo);
  k_splitw<<<(384 * 128 + 255) / 256, 256, 0, stream>>>(W_ih, Wih_hi, Wih_lo, 384 * 128);
  k_splitw<<<(384 * 128 + 255) / 256, 256, 0, stream>>>(W_hh, Whh_hi, Whh_lo, 384 * 128);

  int cur = 0;
  for (int s = 0; s < NSTEPS; ++s) {
    int nxt = cur ^ 1;
    for (int nbase = 0; nbase < N; nbase += CH) {
      int cc = min(CH, N - nbase);
      int cgrid = (cc + 127) / 128;
      k_aggh<<<(cc + 3) / 4, 256, 0, stream>>>(
          (const unsigned*)hP_hi[cur], (const unsigned*)hP_lo[cur], base, cpack,
          (unsigned*)A3hi, (unsigned*)A3lo, nbase, cc);
      k_gemm_a<<<dim3(cgrid, 2), 512, 0, stream>>>(A3hi, A3lo,
          WlT_hi, WlT_lo, b_lin, deg4 + (size_t)nbase * 4, a_hi, a_lo, cc);
      k_grufuse<<<dim3(cgrid, 2), 512, 0, stream>>>(a_hi, a_lo,
          hP_hi[cur], hP_lo[cur], Wih_hi, Wih_lo, Whh_hi, Whh_lo,
          b_ih, b_hh, hP_hi[nxt], hP_lo[nxt], nbase, cc);
    }
    cur ^= 1;
  }

  k_gate<<<(N * 64 + 255) / 256, 256, 0, stream>>>(
      hP_hi[cur], hP_lo[cur], annotation, gate_w, gate_b, gate, N);
  k_mden<<<B, 256, 0, stream>>>(gate, startg, endg, mg, invg);
  k_pool2<<<dim3(B, 2), 256, 0, stream>>>(gate, (const unsigned*)hP_hi[cur],
      (const unsigned*)hP_lo[cur], annotation, startg, endg, mg, invg, readout);
  k_logits<<<1, 64, 0, stream>>>(readout, out_w, out_b, labels, (float*)d_out, B);
}